// Round 7
// baseline (2405.438 us; speedup 1.0000x reference)
//
#include <hip/hip_runtime.h>
#include <hip/hip_bf16.h>

// MoE top-4 of 16 experts, T=8192 tokens, HID=1024, FFN=4096.
// Strategy: exact fp32 gating -> per-expert token lists -> bf16 MFMA grouped
// GEMM1(+exact GELU) -> hdn(bf16, ws) -> bf16 MFMA grouped GEMM2 -> weighted
// fp32 atomicAdd into zeroed d_out.
// ws layout (peak ~400.5 MiB; W1T/W2T share one slot, serialized by stream):
//   SLOT_A bf16 [E][N][K]   134217728 B  (holds W1T for ffn1, then W2T for ffn2)
//   XB  bf16 [T][HID]        16777216 B
//   HDN bf16 [4T][FFN]      268435456 B  (compact expert-segment rows)
//   LTOK/LW/TKE/TKW         4*131072  B
//   CTRL ints (counts/offsets/cursors)  256 B

#define HID 1024
#define FFN 4096
#define NE 16
#define TOPK 4
#define NTOK 8192
#define NPAIR (NTOK*TOPK)

typedef __attribute__((ext_vector_type(4))) float f32x4;
typedef __attribute__((ext_vector_type(8))) short bf16x8;
typedef unsigned short u16;
typedef unsigned int u32;

__device__ __forceinline__ u16 f2bf(float f){
  u32 u = __float_as_uint(f);
  u32 r = (u + 0x7fffu + ((u >> 16) & 1u)) >> 16;   // RNE
  return (u16)r;
}

__device__ __forceinline__ void gload_lds16(const void* g, void* l){
  __builtin_amdgcn_global_load_lds((const __attribute__((address_space(1))) void*)g,
                                   (__attribute__((address_space(3))) void*)l, 16, 0, 0);
}

// ---------------- gating: one wave per token ----------------
__global__ __launch_bounds__(256) void k_gating(const float* __restrict__ x,
    const float* __restrict__ Wg, const float* __restrict__ bg,
    int* __restrict__ counts, int* __restrict__ tke, float* __restrict__ tkw){
  int t    = (blockIdx.x << 2) + (threadIdx.x >> 6);
  int lane = threadIdx.x & 63;
  const float* xr = x + (size_t)t*HID + lane*16;
  float acc[NE];
  #pragma unroll
  for (int e=0;e<NE;e++) acc[e] = 0.f;
  #pragma unroll
  for (int j=0;j<16;j++){
    float xj = xr[j];
    const float* wr = Wg + (size_t)(lane*16 + j)*NE;
    #pragma unroll
    for (int e=0;e<NE;e++) acc[e] += xj * wr[e];
  }
  #pragma unroll
  for (int off=32; off; off>>=1){
    #pragma unroll
    for (int e=0;e<NE;e++) acc[e] += __shfl_xor(acc[e], off);
  }
  if (lane == 0){
    #pragma unroll
    for (int e=0;e<NE;e++) acc[e] += bg[e];
    int te[TOPK]; float tv[TOPK];
    #pragma unroll
    for (int k=0;k<TOPK;k++){
      int bi = 0; float bv = -1e30f;
      #pragma unroll
      for (int e=0;e<NE;e++) if (acc[e] > bv){ bv = acc[e]; bi = e; }
      te[k] = bi; tv[k] = bv; acc[bi] = -1e30f;
    }
    float m = tv[0], s = 0.f, w[TOPK];
    #pragma unroll
    for (int k=0;k<TOPK;k++){ w[k] = expf(tv[k]-m); s += w[k]; }
    float inv = 1.f/s;
    #pragma unroll
    for (int k=0;k<TOPK;k++){
      tke[t*TOPK+k] = te[k];
      tkw[t*TOPK+k] = w[k]*inv;
      atomicAdd(&counts[te[k]], 1);
    }
  }
}

__global__ void k_scan(const int* __restrict__ counts, int* __restrict__ offsets){
  if (threadIdx.x == 0){
    int a = 0;
    for (int e=0;e<NE;e++){ offsets[e] = a; a += counts[e]; }
    offsets[NE] = a;
  }
}

__global__ __launch_bounds__(256) void k_scatter(const int* __restrict__ tke,
    const float* __restrict__ tkw, const int* __restrict__ offsets,
    int* __restrict__ cursors, int* __restrict__ ltok, float* __restrict__ lw){
  int t = blockIdx.x*256 + threadIdx.x;
  #pragma unroll
  for (int k=0;k<TOPK;k++){
    int e = tke[t*TOPK+k];
    int p = atomicAdd(&cursors[e], 1);
    int r = offsets[e] + p;
    ltok[r] = t;
    lw[r]   = tkw[t*TOPK+k];
  }
}

// ---------------- fp32 -> bf16 converts ----------------
__global__ __launch_bounds__(256) void k_cvt_x(const float* __restrict__ x, u16* __restrict__ xb){
  size_t i = ((size_t)blockIdx.x*256 + threadIdx.x) * 8;
  const float4* p = (const float4*)(x + i);
  float4 a = p[0], b = p[1];
  uint4 o;
  o.x = f2bf(a.x) | ((u32)f2bf(a.y) << 16);
  o.y = f2bf(a.z) | ((u32)f2bf(a.w) << 16);
  o.z = f2bf(b.x) | ((u32)f2bf(b.y) << 16);
  o.w = f2bf(b.z) | ((u32)f2bf(b.w) << 16);
  *(uint4*)(xb + i) = o;
}

// transpose+convert: src [R][C] fp32 (per expert z) -> dst [C][R] bf16
// 64x64 tile via LDS; float4 loads, dwordx4 (8xbf16) stores.
__global__ __launch_bounds__(256) void k_wcvt(const float* __restrict__ src,
    u16* __restrict__ dst, int R, int C){
  int e = blockIdx.z;
  src += (size_t)e*R*C;
  dst += (size_t)e*R*C;
  int c0 = blockIdx.x*64, r0 = blockIdx.y*64;
  __shared__ u16 t[64][72];
  int tid = threadIdx.x;
  // load: 4096 elems = 1024 float4; 256 thr x 4 iters
  #pragma unroll
  for (int it=0; it<4; it++){
    int i  = it*256 + tid;
    int rr = i >> 4;              // 0..63
    int c4 = (i & 15) << 2;       // 0,4,..,60
    float4 v = *(const float4*)(src + (size_t)(r0+rr)*C + c0 + c4);
    t[rr][c4+0] = f2bf(v.x);
    t[rr][c4+1] = f2bf(v.y);
    t[rr][c4+2] = f2bf(v.z);
    t[rr][c4+3] = f2bf(v.w);
  }
  __syncthreads();
  // store: 512 items of 8 rows each; 256 thr x 2 iters; 16B per item
  #pragma unroll
  for (int it=0; it<2; it++){
    int i   = it*256 + tid;
    int cc  = i >> 3;             // 0..63
    int rr0 = (i & 7) << 3;       // 0,8,..,56
    uint4 o;
    o.x = (u32)t[rr0+0][cc] | ((u32)t[rr0+1][cc] << 16);
    o.y = (u32)t[rr0+2][cc] | ((u32)t[rr0+3][cc] << 16);
    o.z = (u32)t[rr0+4][cc] | ((u32)t[rr0+5][cc] << 16);
    o.w = (u32)t[rr0+6][cc] | ((u32)t[rr0+7][cc] << 16);
    *(uint4*)(dst + (size_t)(c0+cc)*R + r0 + rr0) = o;
  }
}

// ---------------- grouped GEMM1 + exact GELU -> hdn bf16 ----------------
// tile 128x128, BK=64, 4 waves x 64x64, mfma_f32_16x16x32_bf16
__global__ __launch_bounds__(256) void k_ffn1(
    const u16* __restrict__ xb, const u16* __restrict__ w1t,
    const float* __restrict__ b1,
    const int* __restrict__ counts, const int* __restrict__ offsets,
    const int* __restrict__ ltok, u16* __restrict__ hdn){
  int e = blockIdx.z;
  int cnt = counts[e];
  int row0 = blockIdx.y << 7;
  if (row0 >= cnt) return;
  int n0 = blockIdx.x << 7;
  int soff = offsets[e];
  const int* lt = ltok + soff;

  __shared__ u16 lA[128*64];
  __shared__ u16 lB[128*64];

  int tid = threadIdx.x, lane = tid & 63, wv = tid >> 6;
  int wr = (wv >> 1) << 6, wc = (wv & 1) << 6;
  int l15 = lane & 15, lkhi = (lane >> 4) << 3;

  f32x4 acc[4][4];
  #pragma unroll
  for (int m=0;m<4;m++){
    #pragma unroll
    for (int n=0;n<4;n++) acc[m][n] = (f32x4)0.f;
  }
  const u16* wBp = w1t + ((size_t)e*FFN + n0)*HID;

  for (int k0=0; k0<HID; k0+=64){
    __syncthreads();
    #pragma unroll
    for (int it=0; it<4; it++){
      int idx = it*256 + tid;
      int row = idx >> 3;
      int kc  = (idx & 7) << 3;              // ushort offset in row
      int rc = row0 + row; if (rc > cnt-1) rc = cnt-1;
      int tok = lt[rc];
      gload_lds16(xb  + (size_t)tok*HID + k0 + kc, &lA[idx<<3]);
      gload_lds16(wBp + (size_t)row*HID + k0 + kc, &lB[idx<<3]);
    }
    __syncthreads();
    #pragma unroll
    for (int kk=0; kk<64; kk+=32){
      bf16x8 af[4], bfv[4];
      #pragma unroll
      for (int m=0;m<4;m++) af[m]  = *(const bf16x8*)&lA[(wr + m*16 + l15)*64 + kk + lkhi];
      #pragma unroll
      for (int n=0;n<4;n++) bfv[n] = *(const bf16x8*)&lB[(wc + n*16 + l15)*64 + kk + lkhi];
      #pragma unroll
      for (int m=0;m<4;m++){
        #pragma unroll
        for (int n=0;n<4;n++)
          acc[m][n] = __builtin_amdgcn_mfma_f32_16x16x32_bf16(af[m], bfv[n], acc[m][n], 0,0,0);
      }
    }
  }
  int rhi = (lane >> 4) << 2;
  #pragma unroll
  for (int m=0;m<4;m++){
    int rl = wr + m*16 + rhi;
    #pragma unroll
    for (int j=0;j<4;j++){
      int row = row0 + rl + j;
      if (row < cnt){
        size_t base = (size_t)(soff + row)*FFN;
        #pragma unroll
        for (int n=0;n<4;n++){
          int col = n0 + wc + n*16 + l15;
          float z = acc[m][n][j] + b1[(size_t)e*FFN + col];
          float g = 0.5f*z*(1.0f + erff(z*0.70710678118654752f));  // exact GELU
          hdn[base + col] = f2bf(g);
        }
      }
    }
  }
}

// ---------------- grouped GEMM2 -> weighted atomicAdd into out ----------------
__global__ __launch_bounds__(256) void k_ffn2(
    const u16* __restrict__ hdn, const u16* __restrict__ w2t,
    const float* __restrict__ b2,
    const int* __restrict__ counts, const int* __restrict__ offsets,
    const int* __restrict__ ltok, const float* __restrict__ lw,
    float* __restrict__ out){
  int e = blockIdx.z;
  int cnt = counts[e];
  int row0 = blockIdx.y << 7;
  if (row0 >= cnt) return;
  int n0 = blockIdx.x << 7;
  int soff = offsets[e];

  __shared__ u16 lA[128*64];
  __shared__ u16 lB[128*64];

  int tid = threadIdx.x, lane = tid & 63, wv = tid >> 6;
  int wr = (wv >> 1) << 6, wc = (wv & 1) << 6;
  int l15 = lane & 15, lkhi = (lane >> 4) << 3;

  f32x4 acc[4][4];
  #pragma unroll
  for (int m=0;m<4;m++){
    #pragma unroll
    for (int n=0;n<4;n++) acc[m][n] = (f32x4)0.f;
  }
  const u16* wBp = w2t + ((size_t)e*HID + n0)*FFN;

  for (int k0=0; k0<FFN; k0+=64){
    __syncthreads();
    #pragma unroll
    for (int it=0; it<4; it++){
      int idx = it*256 + tid;
      int row = idx >> 3;
      int kc  = (idx & 7) << 3;
      int rc = row0 + row; if (rc > cnt-1) rc = cnt-1;
      gload_lds16(hdn + (size_t)(soff+rc)*FFN + k0 + kc, &lA[idx<<3]);
      gload_lds16(wBp + (size_t)row*FFN     + k0 + kc, &lB[idx<<3]);
    }
    __syncthreads();
    #pragma unroll
    for (int kk=0; kk<64; kk+=32){
      bf16x8 af[4], bfv[4];
      #pragma unroll
      for (int m=0;m<4;m++) af[m]  = *(const bf16x8*)&lA[(wr + m*16 + l15)*64 + kk + lkhi];
      #pragma unroll
      for (int n=0;n<4;n++) bfv[n] = *(const bf16x8*)&lB[(wc + n*16 + l15)*64 + kk + lkhi];
      #pragma unroll
      for (int m=0;m<4;m++){
        #pragma unroll
        for (int n=0;n<4;n++)
          acc[m][n] = __builtin_amdgcn_mfma_f32_16x16x32_bf16(af[m], bfv[n], acc[m][n], 0,0,0);
      }
    }
  }
  int rhi = (lane >> 4) << 2;
  #pragma unroll
  for (int m=0;m<4;m++){
    int rl = wr + m*16 + rhi;
    #pragma unroll
    for (int j=0;j<4;j++){
      int row = row0 + rl + j;
      if (row < cnt){
        float sw = lw[soff+row];
        int tok  = ltok[soff+row];
        float* orow = out + (size_t)tok*HID;
        #pragma unroll
        for (int n=0;n<4;n++){
          int col = n0 + wc + n*16 + l15;
          atomicAdd(orow + col, sw*(acc[m][n][j] + b2[(size_t)e*HID + col]));
        }
      }
    }
  }
}

extern "C" void kernel_launch(void* const* d_in, const int* in_sizes, int n_in,
                              void* d_out, int out_size, void* d_ws, size_t ws_size,
                              hipStream_t stream){
  const float* x  = (const float*)d_in[0];
  const float* Wg = (const float*)d_in[1];
  const float* bg = (const float*)d_in[2];
  const float* W1 = (const float*)d_in[3];
  const float* b1 = (const float*)d_in[4];
  const float* W2 = (const float*)d_in[5];
  const float* b2 = (const float*)d_in[6];
  float* out = (float*)d_out;

  char* ws = (char*)d_ws;
  size_t off = 0;
  u16* SLOT_A = (u16*)(ws + off); off += (size_t)NE*FFN*HID*2;   // W1T, then W2T
  u16* XB  = (u16*)(ws + off); off += (size_t)NTOK*HID*2;
  u16* HDN = (u16*)(ws + off); off += (size_t)NPAIR*FFN*2;
  int*   LTOK = (int*)(ws + off);   off += (size_t)NPAIR*4;
  float* LW   = (float*)(ws + off); off += (size_t)NPAIR*4;
  int*   TKE  = (int*)(ws + off);   off += (size_t)NPAIR*4;
  float* TKW  = (float*)(ws + off); off += (size_t)NPAIR*4;
  int*   CTRL = (int*)(ws + off);   off += 256;
  // CTRL: [0..15] counts, [16..32] offsets, [33..48] cursors
  int* counts  = CTRL;
  int* offsets = CTRL + 16;
  int* cursors = CTRL + 33;

  (void)hipMemsetAsync(CTRL, 0, 256, stream);
  (void)hipMemsetAsync(out, 0, (size_t)NTOK*HID*sizeof(float), stream);

  k_gating<<<NTOK/4, 256, 0, stream>>>(x, Wg, bg, counts, TKE, TKW);
  k_scan<<<1, 64, 0, stream>>>(counts, offsets);
  k_scatter<<<NTOK/256, 256, 0, stream>>>(TKE, TKW, offsets, cursors, LTOK, LW);
  k_cvt_x<<<(NTOK*HID/8)/256, 256, 0, stream>>>(x, XB);
  // W1 -> SLOT_A, run GEMM1; then W2 -> SLOT_A (stream-serialized), run GEMM2.
  k_wcvt<<<dim3(FFN/64, HID/64, NE), 256, 0, stream>>>(W1, SLOT_A, HID, FFN);
  k_ffn1<<<dim3(FFN/128, NTOK/128, NE), 256, 0, stream>>>(XB, SLOT_A, b1, counts, offsets, LTOK, HDN);
  k_wcvt<<<dim3(HID/64, FFN/64, NE), 256, 0, stream>>>(W2, SLOT_A, FFN, HID);
  k_ffn2<<<dim3(HID/128, NTOK/128, NE), 256, 0, stream>>>(HDN, SLOT_A, b2, counts, offsets, LTOK, LW, out);
}

// Round 8
// 2297.826 us; speedup vs baseline: 1.0468x; 1.0468x over previous
//
#include <hip/hip_runtime.h>
#include <hip/hip_bf16.h>

// MoE top-4 of 16 experts, T=8192 tokens, HID=1024, FFN=4096.
// R7: added T2-style XOR swizzle to k_ffn1/k_ffn2 LDS tiles (16-way bank
// conflict at 128B row stride -> conflict-free). Swizzle is applied on BOTH
// sides (rule #21): pre-swizzled global source for global_load_lds (linear
// LDS dest) + XOR'd ds_read address.
// ws layout (peak ~400.5 MiB; W1T/W2T share one slot, serialized by stream):
//   SLOT_A bf16 [E][N][K]   134217728 B  (holds W1T for ffn1, then W2T for ffn2)
//   XB  bf16 [T][HID]        16777216 B
//   HDN bf16 [4T][FFN]      268435456 B  (compact expert-segment rows)
//   LTOK/LW/TKE/TKW         4*131072  B
//   CTRL ints (counts/offsets/cursors)  256 B

#define HID 1024
#define FFN 4096
#define NE 16
#define TOPK 4
#define NTOK 8192
#define NPAIR (NTOK*TOPK)

typedef __attribute__((ext_vector_type(4))) float f32x4;
typedef __attribute__((ext_vector_type(8))) short bf16x8;
typedef unsigned short u16;
typedef unsigned int u32;

__device__ __forceinline__ u16 f2bf(float f){
  u32 u = __float_as_uint(f);
  u32 r = (u + 0x7fffu + ((u >> 16) & 1u)) >> 16;   // RNE
  return (u16)r;
}

__device__ __forceinline__ void gload_lds16(const void* g, void* l){
  __builtin_amdgcn_global_load_lds((const __attribute__((address_space(1))) void*)g,
                                   (__attribute__((address_space(3))) void*)l, 16, 0, 0);
}

// ---------------- gating: one wave per token ----------------
__global__ __launch_bounds__(256) void k_gating(const float* __restrict__ x,
    const float* __restrict__ Wg, const float* __restrict__ bg,
    int* __restrict__ counts, int* __restrict__ tke, float* __restrict__ tkw){
  int t    = (blockIdx.x << 2) + (threadIdx.x >> 6);
  int lane = threadIdx.x & 63;
  const float* xr = x + (size_t)t*HID + lane*16;
  float acc[NE];
  #pragma unroll
  for (int e=0;e<NE;e++) acc[e] = 0.f;
  #pragma unroll
  for (int j=0;j<16;j++){
    float xj = xr[j];
    const float* wr = Wg + (size_t)(lane*16 + j)*NE;
    #pragma unroll
    for (int e=0;e<NE;e++) acc[e] += xj * wr[e];
  }
  #pragma unroll
  for (int off=32; off; off>>=1){
    #pragma unroll
    for (int e=0;e<NE;e++) acc[e] += __shfl_xor(acc[e], off);
  }
  if (lane == 0){
    #pragma unroll
    for (int e=0;e<NE;e++) acc[e] += bg[e];
    int te[TOPK]; float tv[TOPK];
    #pragma unroll
    for (int k=0;k<TOPK;k++){
      int bi = 0; float bv = -1e30f;
      #pragma unroll
      for (int e=0;e<NE;e++) if (acc[e] > bv){ bv = acc[e]; bi = e; }
      te[k] = bi; tv[k] = bv; acc[bi] = -1e30f;
    }
    float m = tv[0], s = 0.f, w[TOPK];
    #pragma unroll
    for (int k=0;k<TOPK;k++){ w[k] = expf(tv[k]-m); s += w[k]; }
    float inv = 1.f/s;
    #pragma unroll
    for (int k=0;k<TOPK;k++){
      tke[t*TOPK+k] = te[k];
      tkw[t*TOPK+k] = w[k]*inv;
      atomicAdd(&counts[te[k]], 1);
    }
  }
}

__global__ void k_scan(const int* __restrict__ counts, int* __restrict__ offsets){
  if (threadIdx.x == 0){
    int a = 0;
    for (int e=0;e<NE;e++){ offsets[e] = a; a += counts[e]; }
    offsets[NE] = a;
  }
}

__global__ __launch_bounds__(256) void k_scatter(const int* __restrict__ tke,
    const float* __restrict__ tkw, const int* __restrict__ offsets,
    int* __restrict__ cursors, int* __restrict__ ltok, float* __restrict__ lw){
  int t = blockIdx.x*256 + threadIdx.x;
  #pragma unroll
  for (int k=0;k<TOPK;k++){
    int e = tke[t*TOPK+k];
    int p = atomicAdd(&cursors[e], 1);
    int r = offsets[e] + p;
    ltok[r] = t;
    lw[r]   = tkw[t*TOPK+k];
  }
}

// ---------------- fp32 -> bf16 converts ----------------
__global__ __launch_bounds__(256) void k_cvt_x(const float* __restrict__ x, u16* __restrict__ xb){
  size_t i = ((size_t)blockIdx.x*256 + threadIdx.x) * 8;
  const float4* p = (const float4*)(x + i);
  float4 a = p[0], b = p[1];
  uint4 o;
  o.x = f2bf(a.x) | ((u32)f2bf(a.y) << 16);
  o.y = f2bf(a.z) | ((u32)f2bf(a.w) << 16);
  o.z = f2bf(b.x) | ((u32)f2bf(b.y) << 16);
  o.w = f2bf(b.z) | ((u32)f2bf(b.w) << 16);
  *(uint4*)(xb + i) = o;
}

// transpose+convert: src [R][C] fp32 (per expert z) -> dst [C][R] bf16
// 64x64 tile via LDS; float4 loads, dwordx4 (8xbf16) stores.
__global__ __launch_bounds__(256) void k_wcvt(const float* __restrict__ src,
    u16* __restrict__ dst, int R, int C){
  int e = blockIdx.z;
  src += (size_t)e*R*C;
  dst += (size_t)e*R*C;
  int c0 = blockIdx.x*64, r0 = blockIdx.y*64;
  __shared__ u16 t[64][72];
  int tid = threadIdx.x;
  // load: 4096 elems = 1024 float4; 256 thr x 4 iters
  #pragma unroll
  for (int it=0; it<4; it++){
    int i  = it*256 + tid;
    int rr = i >> 4;              // 0..63
    int c4 = (i & 15) << 2;       // 0,4,..,60
    float4 v = *(const float4*)(src + (size_t)(r0+rr)*C + c0 + c4);
    t[rr][c4+0] = f2bf(v.x);
    t[rr][c4+1] = f2bf(v.y);
    t[rr][c4+2] = f2bf(v.z);
    t[rr][c4+3] = f2bf(v.w);
  }
  __syncthreads();
  // store: 512 items of 8 rows each; 256 thr x 2 iters; 16B per item
  #pragma unroll
  for (int it=0; it<2; it++){
    int i   = it*256 + tid;
    int cc  = i >> 3;             // 0..63
    int rr0 = (i & 7) << 3;       // 0,8,..,56
    uint4 o;
    o.x = (u32)t[rr0+0][cc] | ((u32)t[rr0+1][cc] << 16);
    o.y = (u32)t[rr0+2][cc] | ((u32)t[rr0+3][cc] << 16);
    o.z = (u32)t[rr0+4][cc] | ((u32)t[rr0+5][cc] << 16);
    o.w = (u32)t[rr0+6][cc] | ((u32)t[rr0+7][cc] << 16);
    *(uint4*)(dst + (size_t)(c0+cc)*R + r0 + rr0) = o;
  }
}

// ---------------- grouped GEMM1 + exact GELU -> hdn bf16 ----------------
// tile 128x128, BK=64, 4 waves x 64x64, mfma_f32_16x16x32_bf16
// LDS layout swizzled: logical (row, k[u16]) lives at u16 offset
//   row*64 + (k ^ ((row&7)<<3)).  Staged via linear gload_lds dest +
//   inverse-permuted global source (same involution).
__global__ __launch_bounds__(256) void k_ffn1(
    const u16* __restrict__ xb, const u16* __restrict__ w1t,
    const float* __restrict__ b1,
    const int* __restrict__ counts, const int* __restrict__ offsets,
    const int* __restrict__ ltok, u16* __restrict__ hdn){
  int e = blockIdx.z;
  int cnt = counts[e];
  int row0 = blockIdx.y << 7;
  if (row0 >= cnt) return;
  int n0 = blockIdx.x << 7;
  int soff = offsets[e];
  const int* lt = ltok + soff;

  __shared__ u16 lA[128*64];
  __shared__ u16 lB[128*64];

  int tid = threadIdx.x, lane = tid & 63, wv = tid >> 6;
  int wr = (wv >> 1) << 6, wc = (wv & 1) << 6;
  int l15 = lane & 15, lkhi = (lane >> 4) << 3;

  f32x4 acc[4][4];
  #pragma unroll
  for (int m=0;m<4;m++){
    #pragma unroll
    for (int n=0;n<4;n++) acc[m][n] = (f32x4)0.f;
  }
  const u16* wBp = w1t + ((size_t)e*FFN + n0)*HID;

  for (int k0=0; k0<HID; k0+=64){
    __syncthreads();
    #pragma unroll
    for (int it=0; it<4; it++){
      int idx = it*256 + tid;
      int row = idx >> 3;
      int kc  = ((idx & 7) ^ (row & 7)) << 3;   // swizzled ushort offset in row
      int rc = row0 + row; if (rc > cnt-1) rc = cnt-1;
      int tok = lt[rc];
      gload_lds16(xb  + (size_t)tok*HID + k0 + kc, &lA[idx<<3]);
      gload_lds16(wBp + (size_t)row*HID + k0 + kc, &lB[idx<<3]);
    }
    __syncthreads();
    #pragma unroll
    for (int kk=0; kk<64; kk+=32){
      bf16x8 af[4], bfv[4];
      #pragma unroll
      for (int m=0;m<4;m++){
        int ra = wr + m*16 + l15;
        af[m]  = *(const bf16x8*)&lA[ra*64 + ((kk + lkhi) ^ ((ra&7)<<3))];
      }
      #pragma unroll
      for (int n=0;n<4;n++){
        int rb = wc + n*16 + l15;
        bfv[n] = *(const bf16x8*)&lB[rb*64 + ((kk + lkhi) ^ ((rb&7)<<3))];
      }
      #pragma unroll
      for (int m=0;m<4;m++){
        #pragma unroll
        for (int n=0;n<4;n++)
          acc[m][n] = __builtin_amdgcn_mfma_f32_16x16x32_bf16(af[m], bfv[n], acc[m][n], 0,0,0);
      }
    }
  }
  int rhi = (lane >> 4) << 2;
  #pragma unroll
  for (int m=0;m<4;m++){
    int rl = wr + m*16 + rhi;
    #pragma unroll
    for (int j=0;j<4;j++){
      int row = row0 + rl + j;
      if (row < cnt){
        size_t base = (size_t)(soff + row)*FFN;
        #pragma unroll
        for (int n=0;n<4;n++){
          int col = n0 + wc + n*16 + l15;
          float z = acc[m][n][j] + b1[(size_t)e*FFN + col];
          float g = 0.5f*z*(1.0f + erff(z*0.70710678118654752f));  // exact GELU
          hdn[base + col] = f2bf(g);
        }
      }
    }
  }
}

// ---------------- grouped GEMM2 -> weighted atomicAdd into out ----------------
__global__ __launch_bounds__(256) void k_ffn2(
    const u16* __restrict__ hdn, const u16* __restrict__ w2t,
    const float* __restrict__ b2,
    const int* __restrict__ counts, const int* __restrict__ offsets,
    const int* __restrict__ ltok, const float* __restrict__ lw,
    float* __restrict__ out){
  int e = blockIdx.z;
  int cnt = counts[e];
  int row0 = blockIdx.y << 7;
  if (row0 >= cnt) return;
  int n0 = blockIdx.x << 7;
  int soff = offsets[e];

  __shared__ u16 lA[128*64];
  __shared__ u16 lB[128*64];

  int tid = threadIdx.x, lane = tid & 63, wv = tid >> 6;
  int wr = (wv >> 1) << 6, wc = (wv & 1) << 6;
  int l15 = lane & 15, lkhi = (lane >> 4) << 3;

  f32x4 acc[4][4];
  #pragma unroll
  for (int m=0;m<4;m++){
    #pragma unroll
    for (int n=0;n<4;n++) acc[m][n] = (f32x4)0.f;
  }
  const u16* wBp = w2t + ((size_t)e*HID + n0)*FFN;

  for (int k0=0; k0<FFN; k0+=64){
    __syncthreads();
    #pragma unroll
    for (int it=0; it<4; it++){
      int idx = it*256 + tid;
      int row = idx >> 3;
      int kc  = ((idx & 7) ^ (row & 7)) << 3;   // swizzled ushort offset in row
      int rc = row0 + row; if (rc > cnt-1) rc = cnt-1;
      gload_lds16(hdn + (size_t)(soff+rc)*FFN + k0 + kc, &lA[idx<<3]);
      gload_lds16(wBp + (size_t)row*FFN     + k0 + kc, &lB[idx<<3]);
    }
    __syncthreads();
    #pragma unroll
    for (int kk=0; kk<64; kk+=32){
      bf16x8 af[4], bfv[4];
      #pragma unroll
      for (int m=0;m<4;m++){
        int ra = wr + m*16 + l15;
        af[m]  = *(const bf16x8*)&lA[ra*64 + ((kk + lkhi) ^ ((ra&7)<<3))];
      }
      #pragma unroll
      for (int n=0;n<4;n++){
        int rb = wc + n*16 + l15;
        bfv[n] = *(const bf16x8*)&lB[rb*64 + ((kk + lkhi) ^ ((rb&7)<<3))];
      }
      #pragma unroll
      for (int m=0;m<4;m++){
        #pragma unroll
        for (int n=0;n<4;n++)
          acc[m][n] = __builtin_amdgcn_mfma_f32_16x16x32_bf16(af[m], bfv[n], acc[m][n], 0,0,0);
      }
    }
  }
  int rhi = (lane >> 4) << 2;
  #pragma unroll
  for (int m=0;m<4;m++){
    int rl = wr + m*16 + rhi;
    #pragma unroll
    for (int j=0;j<4;j++){
      int row = row0 + rl + j;
      if (row < cnt){
        float sw = lw[soff+row];
        int tok  = ltok[soff+row];
        float* orow = out + (size_t)tok*HID;
        #pragma unroll
        for (int n=0;n<4;n++){
          int col = n0 + wc + n*16 + l15;
          atomicAdd(orow + col, sw*(acc[m][n][j] + b2[(size_t)e*HID + col]));
        }
      }
    }
  }
}

extern "C" void kernel_launch(void* const* d_in, const int* in_sizes, int n_in,
                              void* d_out, int out_size, void* d_ws, size_t ws_size,
                              hipStream_t stream){
  const float* x  = (const float*)d_in[0];
  const float* Wg = (const float*)d_in[1];
  const float* bg = (const float*)d_in[2];
  const float* W1 = (const float*)d_in[3];
  const float* b1 = (const float*)d_in[4];
  const float* W2 = (const float*)d_in[5];
  const float* b2 = (const float*)d_in[6];
  float* out = (float*)d_out;

  char* ws = (char*)d_ws;
  size_t off = 0;
  u16* SLOT_A = (u16*)(ws + off); off += (size_t)NE*FFN*HID*2;   // W1T, then W2T
  u16* XB  = (u16*)(ws + off); off += (size_t)NTOK*HID*2;
  u16* HDN = (u16*)(ws + off); off += (size_t)NPAIR*FFN*2;
  int*   LTOK = (int*)(ws + off);   off += (size_t)NPAIR*4;
  float* LW   = (float*)(ws + off); off += (size_t)NPAIR*4;
  int*   TKE  = (int*)(ws + off);   off += (size_t)NPAIR*4;
  float* TKW  = (float*)(ws + off); off += (size_t)NPAIR*4;
  int*   CTRL = (int*)(ws + off);   off += 256;
  // CTRL: [0..15] counts, [16..32] offsets, [33..48] cursors
  int* counts  = CTRL;
  int* offsets = CTRL + 16;
  int* cursors = CTRL + 33;

  (void)hipMemsetAsync(CTRL, 0, 256, stream);
  (void)hipMemsetAsync(out, 0, (size_t)NTOK*HID*sizeof(float), stream);

  k_gating<<<NTOK/4, 256, 0, stream>>>(x, Wg, bg, counts, TKE, TKW);
  k_scan<<<1, 64, 0, stream>>>(counts, offsets);
  k_scatter<<<NTOK/256, 256, 0, stream>>>(TKE, TKW, offsets, cursors, LTOK, LW);
  k_cvt_x<<<(NTOK*HID/8)/256, 256, 0, stream>>>(x, XB);
  // W1 -> SLOT_A, run GEMM1; then W2 -> SLOT_A (stream-serialized), run GEMM2.
  k_wcvt<<<dim3(FFN/64, HID/64, NE), 256, 0, stream>>>(W1, SLOT_A, HID, FFN);
  k_ffn1<<<dim3(FFN/128, NTOK/128, NE), 256, 0, stream>>>(XB, SLOT_A, b1, counts, offsets, LTOK, HDN);
  k_wcvt<<<dim3(HID/64, FFN/64, NE), 256, 0, stream>>>(W2, SLOT_A, FFN, HID);
  k_ffn2<<<dim3(HID/128, NTOK/128, NE), 256, 0, stream>>>(HDN, SLOT_A, b2, counts, offsets, LTOK, LW, out);
}